// Round 11
// baseline (496.708 us; speedup 1.0000x reference)
//
#include <hip/hip_runtime.h>
#include <math.h>

typedef unsigned short u16;
typedef unsigned int u32;
typedef short bf16x8 __attribute__((ext_vector_type(8)));
typedef float f32x4 __attribute__((ext_vector_type(4)));
typedef u16 u16x4 __attribute__((ext_vector_type(4)));
typedef u16 u16x8 __attribute__((ext_vector_type(8)));
typedef u32 u32x4 __attribute__((ext_vector_type(4)));

// ---------- bf16 <-> f32 helpers ----------
static __device__ __forceinline__ float b2f(u16 u) {
  union { u32 i; float f; } v; v.i = ((u32)u) << 16; return v.f;
}
static __device__ __forceinline__ u16 f2b(float f) {
  union { float f; u32 i; } v; v.f = f;
  u32 r = v.i + 0x7fffu + ((v.i >> 16) & 1u);
  return (u16)(r >> 16);
}
static __device__ __forceinline__ void cvt16(const float* src, u16* dst, int i) {
  f32x4 v = *(const f32x4*)(src + (size_t)i * 4);
  u16x4 w; w.x = f2b(v.x); w.y = f2b(v.y); w.z = f2b(v.z); w.w = f2b(v.w);
  *(u16x4*)(dst + (size_t)i * 4) = w;
}

// ---------- async global -> LDS, 16B per lane ----------
static __device__ __forceinline__ void g2l16(const void* g, void* l) {
  typedef __attribute__((address_space(1))) const void gvoid;
  typedef __attribute__((address_space(3))) void lvoid;
  __builtin_amdgcn_global_load_lds((gvoid*)g, (lvoid*)l, 16, 0, 0);
}

// =====================================================================
// Standalone weight convert (tier-2/3).
// =====================================================================
__global__ __launch_bounds__(256)
void wcvt_kernel(const float* __restrict__ src, u16* __restrict__ dst, int n4)
{
  for (int i = blockIdx.x * 256 + threadIdx.x; i < n4; i += gridDim.x * 256)
    cvt16(src, dst, i);
}

// =====================================================================
// prep: blocks 0..9215 LayerNorm; 9216..10239 wq cvt; 10240..11263 wkv cvt.
// =====================================================================
__global__ __launch_bounds__(256)
void prep_kernel(const float* __restrict__ x, const float* __restrict__ mv,
                 u16* __restrict__ xf, u16* __restrict__ xm,
                 const float* __restrict__ wq, u16* __restrict__ wqs,
                 const float* __restrict__ wkv, u16* __restrict__ wkvs)
{
  const int b = blockIdx.x, tid = threadIdx.x;
  if (b >= 9216) {
    if (b < 10240) {
      const int n4 = 3072 * 3072 / 4;
      for (int i = (b - 9216) * 256 + tid; i < n4; i += 1024 * 256) cvt16(wq, wqs, i);
    } else {
      const int n4 = 6144 * 3072 / 4;
      for (int i = (b - 10240) * 256 + tid; i < n4; i += 1024 * 256) cvt16(wkv, wkvs, i);
    }
    return;
  }
  const float* src; u16* dst;
  if (b < 8192) { src = x + (size_t)b * 3072;          dst = xf + (size_t)b * 3072; }
  else          { src = mv + (size_t)(b - 8192) * 3072; dst = xm + (size_t)(b - 8192) * 3072; }

  f32x4 vals[3];
  #pragma unroll
  for (int i = 0; i < 3; ++i) vals[i] = *(const f32x4*)(src + tid * 4 + i * 1024);

  float s1 = 0.f, s2 = 0.f;
  #pragma unroll
  for (int i = 0; i < 3; ++i) {
    f32x4 v = vals[i];
    s1 += v.x + v.y + v.z + v.w;
    s2 += v.x * v.x + v.y * v.y + v.z * v.z + v.w * v.w;
  }
  #pragma unroll
  for (int o = 32; o > 0; o >>= 1) { s1 += __shfl_down(s1, o); s2 += __shfl_down(s2, o); }
  __shared__ float r1[4], r2[4];
  const int wv = tid >> 6, ln = tid & 63;
  if (ln == 0) { r1[wv] = s1; r2[wv] = s2; }
  __syncthreads();
  const float t1 = r1[0] + r1[1] + r1[2] + r1[3];
  const float t2 = r2[0] + r2[1] + r2[2] + r2[3];
  const float mu = t1 * (1.f / 3072.f);
  const float rs = rsqrtf(t2 * (1.f / 3072.f) - mu * mu + 1e-6f);
  #pragma unroll
  for (int i = 0; i < 3; ++i) {
    f32x4 v = vals[i]; u16x4 w;
    w.x = f2b((v.x - mu) * rs); w.y = f2b((v.y - mu) * rs);
    w.z = f2b((v.z - mu) * rs); w.w = f2b((v.w - mu) * rs);
    *(u16x4*)(dst + tid * 4 + i * 1024) = w;
  }
}

// =====================================================================
// gemm8p (race-fixed): 256x256 tile, BK=64, 8 waves (2M x 4N), per-wave
// 128x64. LDS 128 KB: [A|B] x [dbuf d] x [half h] x 128 rows x 64 elems.
// Region read windows (iter i, d0=tile t=2i, d1=tile t+1):
//   A-d0: P1,P3   A-d1: P5,P7   B-d0: P1,P2,P4   B-d1: P5,P6,P8
// Staging (each SG after its region's last reader, barrier-separated):
//   P1:(t+1)Ah1->d1  P2:(t+1)Bh0->d1  P3:(t+1)Bh1->d1  P4:(t+2)Ah0->d0
//   P5:(t+2)Ah1->d0  P6:(t+2)Bh0->d0  P7:(t+2)Bh1->d0  P8:(t+3)Ah0->d1
// vmcnt(2) at P4 retires tile t+1's 8 loads exactly (entry=2 outstanding
// +P1..P3's 6 +P4's 2 = 10 -> keep 2); P8 symmetric for t+2. Final iter:
// P4 vmcnt(0), P8 none. Prologue: t0 x4 halves + t1Ah0, vmcnt(2).
// =====================================================================
template<int EPI, typename TOUT>
__global__ __launch_bounds__(512, 1)
void gemm8p(const u16* __restrict__ A, const u16* __restrict__ Wb,
            const float* __restrict__ bias, const float* __restrict__ mask,
            TOUT* __restrict__ C, int M, int N, int K)
{
  __shared__ __align__(16) u16 L[65536];   // 128 KB
  const int tid = threadIdx.x, wave = tid >> 6, lane = tid & 63;
  const int wr = wave >> 2, wc = wave & 3;       // 2 x 4 wave grid
  const int lr = lane & 15, lg = lane >> 4;

  const int nwg = gridDim.x;
  const int bid = (blockIdx.x & 7) * (nwg >> 3) + (blockIdx.x >> 3);
  const int nbx = N >> 8;
  const int brow = (bid / nbx) << 8;
  const int bcol = (bid % nbx) << 8;

  const u16* gA = A + (size_t)brow * K;
  const u16* gB = Wb + (size_t)bcol * K;

  // staging: round = 512 thr x 16B = 64 rows x 128B; 2 rounds/half-tile
  const int sr = tid >> 3;                        // 0..63 row in round
  const int sc = 8 * ((tid & 7) ^ (sr & 7));      // pre-swizzled src col
  // fragment read chunk offsets (phys = logical ^ (row&7))
  const int ch0 = 8 * (lg ^ (lr & 7));
  const int ch1 = 8 * ((4 + lg) ^ (lr & 7));

  f32x4 acc[8][4] = {};

  // stage one half-tile: sel 0=A,1=B; dbuf d, half h, K-tile T (2 gloads)
  auto SG = [&](int sel, int d, int h, int T) {
    const u16* g = (sel == 0 ? gA : gB) + (size_t)(h * 128 + sr) * K + T * 64 + sc;
    u16* l = &L[sel * 32768 + (d * 2 + h) * 8192 + tid * 8];
    g2l16(g, l);
    g2l16(g + (size_t)64 * K, l + 4096);
  };
  auto LDA = [&](int d, int mh, bf16x8 a[4][2]) {
    const u16* base = &L[(d * 2 + wr) * 8192 + mh * 4096 + lr * 64];
    #pragma unroll
    for (int mm = 0; mm < 4; ++mm) {
      a[mm][0] = *(const bf16x8*)&base[mm * 1024 + ch0];
      a[mm][1] = *(const bf16x8*)&base[mm * 1024 + ch1];
    }
  };
  auto LDB = [&](int d, int nh, bf16x8 b[2][2]) {
    const u16* base = &L[32768 + (d * 2 + (wc >> 1)) * 8192 + (wc & 1) * 4096 + nh * 2048 + lr * 64];
    #pragma unroll
    for (int nn = 0; nn < 2; ++nn) {
      b[nn][0] = *(const bf16x8*)&base[nn * 1024 + ch0];
      b[nn][1] = *(const bf16x8*)&base[nn * 1024 + ch1];
    }
  };

#define MM8P(mh, nh, a, b)                                                     \
  __builtin_amdgcn_s_setprio(1);                                               \
  _Pragma("unroll")                                                            \
  for (int mm = 0; mm < 4; ++mm)                                               \
    _Pragma("unroll")                                                          \
    for (int nn = 0; nn < 2; ++nn) {                                           \
      acc[(mh)*4+mm][(nh)*2+nn] = __builtin_amdgcn_mfma_f32_16x16x32_bf16(     \
          a[mm][0], b[nn][0], acc[(mh)*4+mm][(nh)*2+nn], 0, 0, 0);             \
      acc[(mh)*4+mm][(nh)*2+nn] = __builtin_amdgcn_mfma_f32_16x16x32_bf16(     \
          a[mm][1], b[nn][1], acc[(mh)*4+mm][(nh)*2+nn], 0, 0, 0);             \
    }                                                                          \
  __builtin_amdgcn_s_setprio(0);

#define BAR_PRE()                                                              \
  asm volatile("" ::: "memory");                                               \
  __builtin_amdgcn_s_barrier();                                                \
  asm volatile("s_waitcnt lgkmcnt(0)" ::: "memory");                           \
  __builtin_amdgcn_sched_barrier(0);

#define BAR_POST()                                                             \
  asm volatile("" ::: "memory");                                               \
  __builtin_amdgcn_s_barrier();                                                \
  __builtin_amdgcn_sched_barrier(0);

  // prologue: t0 all 4 halves -> d0; t1 Ah0 -> d1; retire t0 (keep 2)
  SG(0, 0, 0, 0); SG(0, 0, 1, 0); SG(1, 0, 0, 0); SG(1, 0, 1, 0);
  SG(0, 1, 0, 1);
  asm volatile("s_waitcnt vmcnt(2)" ::: "memory");
  __builtin_amdgcn_s_barrier();
  __builtin_amdgcn_sched_barrier(0);

  const int NI = K >> 7;     // iterations over K-tile pairs (BK=64)
  for (int i = 0; i < NI; ++i) {
    const int t = 2 * i;
    const bool pf = (i + 1) < NI;
    bf16x8 a[4][2], b[2][2];

    // P1: read A(d0,mh0)+B(d0,nh0); stage (t+1)A h1 -> d1
    LDA(0, 0, a); LDB(0, 0, b);
    SG(0, 1, 1, t + 1);
    BAR_PRE(); MM8P(0, 0, a, b); BAR_POST();

    // P2: read B(d0,nh1); stage (t+1)B h0 -> d1
    LDB(0, 1, b);
    SG(1, 1, 0, t + 1);
    BAR_PRE(); MM8P(0, 1, a, b); BAR_POST();

    // P3: read A(d0,mh1); stage (t+1)B h1 -> d1
    LDA(0, 1, a);
    SG(1, 1, 1, t + 1);
    BAR_PRE(); MM8P(1, 1, a, b); BAR_POST();

    // P4: read B(d0,nh0); stage (t+2)A h0 -> d0; retire tile t+1
    LDB(0, 0, b);
    if (pf) SG(0, 0, 0, t + 2);
    BAR_PRE(); MM8P(1, 0, a, b);
    if (pf) { asm volatile("s_waitcnt vmcnt(2)" ::: "memory"); }
    else    { asm volatile("s_waitcnt vmcnt(0)" ::: "memory"); }
    BAR_POST();

    // P5: read A(d1,mh0)+B(d1,nh0); stage (t+2)A h1 -> d0
    LDA(1, 0, a); LDB(1, 0, b);
    if (pf) SG(0, 0, 1, t + 2);
    BAR_PRE(); MM8P(0, 0, a, b); BAR_POST();

    // P6: read B(d1,nh1); stage (t+2)B h0 -> d0
    LDB(1, 1, b);
    if (pf) SG(1, 0, 0, t + 2);
    BAR_PRE(); MM8P(0, 1, a, b); BAR_POST();

    // P7: read A(d1,mh1); stage (t+2)B h1 -> d0
    LDA(1, 1, a);
    if (pf) SG(1, 0, 1, t + 2);
    BAR_PRE(); MM8P(1, 1, a, b); BAR_POST();

    // P8: read B(d1,nh0); stage (t+3)A h0 -> d1; retire tile t+2
    LDB(1, 0, b);
    if (pf) SG(0, 1, 0, t + 3);
    BAR_PRE(); MM8P(1, 0, a, b);
    if (pf) { asm volatile("s_waitcnt vmcnt(2)" ::: "memory"); }
    BAR_POST();
  }

#undef MM8P
#undef BAR_PRE
#undef BAR_POST

  // epilogue: D row = 4*(lane>>4)+i, col = lane&15 (m89-verified)
  #pragma unroll
  for (int m = 0; m < 8; ++m) {
    const int row = brow + wr * 128 + m * 16 + (lg << 2);
    #pragma unroll
    for (int n = 0; n < 4; ++n) {
      const int col = bcol + wc * 64 + n * 16 + lr;
      const float bv = bias[col];
      #pragma unroll
      for (int i = 0; i < 4; ++i) {
        float v = acc[m][n][i] + bv;
        if (EPI == 1) v *= mask[row + i];
        if constexpr (__is_same(TOUT, u16))
          C[(size_t)(row + i) * N + col] = f2b(v);
        else
          C[(size_t)(row + i) * N + col] = v;
      }
    }
  }
}

// =====================================================================
// gemm256 (R5-verified): 256x128 tile, BK=32, 4 waves, 3-buf rotation,
// counted vmcnt(6). Used for the KV GEMM (small M).
// =====================================================================
template<int EPI, typename TOUT>
__global__ __launch_bounds__(256, 2)
void gemm256(const u16* __restrict__ A, const u16* __restrict__ Wb,
             const float* __restrict__ bias, const float* __restrict__ mask,
             TOUT* __restrict__ C, int M, int N, int K)
{
  __shared__ __align__(16) u16 L[36864];
  const int tid = threadIdx.x, wave = tid >> 6, lane = tid & 63;

  const int nwg = gridDim.x;
  const int bid = (blockIdx.x & 7) * (nwg >> 3) + (blockIdx.x >> 3);
  const int nbx = N >> 7;
  const int brow = (bid / nbx) << 8;
  const int bcol = (bid % nbx) << 7;
  const int wr = wave >> 1, wc = wave & 1;

  const u16* gA = A + (size_t)brow * K;
  const u16* gB = Wb + (size_t)bcol * K;

  const int srow = tid >> 2;
  const int scol = 8 * ((lane & 3) ^ ((lane >> 3) & 3));
  const int rcoff = 8 * ((lane >> 4) ^ ((lane >> 1) & 3));

  f32x4 acc[8][4] = {};

  auto STAGE = [&](int b, int tk) {
    u16* bufA = &L[b * 12288];
    u16* bufB = bufA + 8192;
    const u16* srcA = gA + tk + scol;
    const u16* srcB = gB + tk + scol;
    #pragma unroll
    for (int j = 0; j < 4; ++j)
      g2l16(srcA + (size_t)(j * 64 + srow) * K, bufA + (j * 64 + wave * 16) * 32);
    #pragma unroll
    for (int j = 0; j < 2; ++j)
      g2l16(srcB + (size_t)(j * 64 + srow) * K, bufB + (j * 64 + wave * 16) * 32);
  };

  auto COMPUTE = [&](int b) {
    const u16* bufA = &L[b * 12288];
    const u16* bufB = bufA + 8192;
    bf16x8 af[8], bfv[4];
    #pragma unroll
    for (int m = 0; m < 8; ++m)
      af[m] = *(const bf16x8*)&bufA[(wr * 128 + m * 16 + (lane & 15)) * 32 + rcoff];
    #pragma unroll
    for (int n = 0; n < 4; ++n)
      bfv[n] = *(const bf16x8*)&bufB[(wc * 64 + n * 16 + (lane & 15)) * 32 + rcoff];
    __builtin_amdgcn_s_setprio(1);
    #pragma unroll
    for (int m = 0; m < 8; ++m)
      #pragma unroll
      for (int n = 0; n < 4; ++n)
        acc[m][n] = __builtin_amdgcn_mfma_f32_16x16x32_bf16(af[m], bfv[n], acc[m][n], 0, 0, 0);
    __builtin_amdgcn_s_setprio(0);
  };

  STAGE(0, 0);
  STAGE(1, 32);
  asm volatile("s_waitcnt vmcnt(6)" ::: "memory");
  __builtin_amdgcn_s_barrier();
  __builtin_amdgcn_sched_barrier(0);

  const int NT = K >> 5;
  int cur = 0;
  for (int t = 0; t < NT; ++t) {
    const bool pf = (t + 2) < NT;
    if (pf) {
      int nb = cur + 2; if (nb >= 3) nb -= 3;
      STAGE(nb, (t + 2) << 5);
    }
    COMPUTE(cur);
    if (pf) asm volatile("s_waitcnt vmcnt(6)" ::: "memory");
    else    asm volatile("s_waitcnt vmcnt(0)" ::: "memory");
    __builtin_amdgcn_s_barrier();
    __builtin_amdgcn_sched_barrier(0);
    if (++cur == 3) cur = 0;
  }

  #pragma unroll
  for (int m = 0; m < 8; ++m) {
    const int row = brow + wr * 128 + m * 16 + ((lane >> 4) << 2);
    #pragma unroll
    for (int n = 0; n < 4; ++n) {
      const int col = bcol + wc * 64 + n * 16 + (lane & 15);
      const float bv = bias[col];
      #pragma unroll
      for (int i = 0; i < 4; ++i) {
        float v = acc[m][n][i] + bv;
        if (EPI == 1) v *= mask[row + i];
        if constexpr (__is_same(TOUT, u16))
          C[(size_t)(row + i) * N + col] = f2b(v);
        else
          C[(size_t)(row + i) * N + col] = v;
      }
    }
  }
}

// =====================================================================
// Fallback mixed GEMM (W fp32 reg-staged cvt) — tier-3 only.
// =====================================================================
template<int EPI, typename TOUT>
__global__ __launch_bounds__(256)
void gemm_mixed(const u16* __restrict__ A, const float* __restrict__ W,
                const float* __restrict__ bias, const float* __restrict__ mask,
                TOUT* __restrict__ C, int M, int N, int K)
{
  __shared__ __align__(16) u16 lA[4096];
  __shared__ __align__(16) u16 lB[4096];
  const int tid = threadIdx.x, wave = tid >> 6, lane = tid & 63;
  const int nbx = N >> 7;
  const int brow = (blockIdx.x / nbx) << 7;
  const int bcol = (blockIdx.x % nbx) << 7;
  const int wr = wave >> 1, wc = wave & 1;

  f32x4 acc[4][4] = {};
  const u16* gA = A + (size_t)brow * K;
  const float* gB = W + (size_t)bcol * K;
  const int br = tid >> 1, bk0 = (tid & 1) << 4;
  const float* bsrc0 = gB + (size_t)br * K + bk0;
  u16* bdst = &lB[br * 32 + bk0];

  for (int tk = 0; tk < K; tk += 32) {
    #pragma unroll
    for (int j = 0; j < 2; ++j) {
      const int c = j * 256 + wave * 64 + lane;
      const int r = c >> 2, k8 = (c & 3) << 3;
      g2l16(gA + (size_t)r * K + tk + k8, (char*)lA + (size_t)(j * 256 + wave * 64) * 16);
    }
    {
      const float* src = bsrc0 + tk;
      #pragma unroll
      for (int j = 0; j < 4; ++j) {
        f32x4 v = *(const f32x4*)(src + 4 * j);
        u16x4 w; w.x = f2b(v.x); w.y = f2b(v.y); w.z = f2b(v.z); w.w = f2b(v.w);
        *(u16x4*)(bdst + 4 * j) = w;
      }
    }
    __syncthreads();

    bf16x8 af[4], bfr[4];
    #pragma unroll
    for (int m = 0; m < 4; ++m)
      af[m] = *(const bf16x8*)&lA[(wr * 64 + m * 16 + (lane & 15)) * 32 + ((lane >> 4) << 3)];
    #pragma unroll
    for (int n = 0; n < 4; ++n)
      bfr[n] = *(const bf16x8*)&lB[(wc * 64 + n * 16 + (lane & 15)) * 32 + ((lane >> 4) << 3)];
    #pragma unroll
    for (int m = 0; m < 4; ++m)
      #pragma unroll
      for (int n = 0; n < 4; ++n)
        acc[m][n] = __builtin_amdgcn_mfma_f32_16x16x32_bf16(af[m], bfr[n], acc[m][n], 0, 0, 0);
    __syncthreads();
  }

  #pragma unroll
  for (int m = 0; m < 4; ++m) {
    const int row = brow + wr * 64 + m * 16 + ((lane >> 4) << 2);
    #pragma unroll
    for (int n = 0; n < 4; ++n) {
      const int col = bcol + wc * 64 + n * 16 + (lane & 15);
      const float bv = bias[col];
      #pragma unroll
      for (int i = 0; i < 4; ++i) {
        float v = acc[m][n][i] + bv;
        if (EPI == 1) v *= mask[row + i];
        if constexpr (__is_same(TOUT, u16))
          C[(size_t)(row + i) * N + col] = f2b(v);
        else
          C[(size_t)(row + i) * N + col] = v;
      }
    }
  }
}

// =====================================================================
// attn_wcvt: blocks 0..767 MFMA attention (verified R7 body);
// blocks 768..1791 wo fp32->bf16.
// =====================================================================
__global__ __launch_bounds__(256)
void attn_wcvt(const u16* __restrict__ qb, const u16* __restrict__ kvb,
               const float* __restrict__ qw, const float* __restrict__ kw,
               u16* __restrict__ attnb,
               const float* __restrict__ wo, u16* __restrict__ wos)
{
  __shared__ __align__(16) u16 Kn[32 * 136];
  __shared__ __align__(16) u16 Vt[128 * 40];
  __shared__ __align__(16) u16 Pl[256 * 40];
  __shared__ __align__(16) u16 Ol[4][16 * 136];
  const int tid = threadIdx.x;
  if (blockIdx.x >= 768) {
    const int n4 = 3072 * 3072 / 4;
    for (int i = (blockIdx.x - 768) * 256 + tid; i < n4; i += 1024 * 256)
      cvt16(wo, wos, i);
    return;
  }
  const int wave = tid >> 6, lane = tid & 63;
  const int h = blockIdx.x % 24;
  const int bt = blockIdx.x / 24;

  {
    const int n = tid >> 3, sub = tid & 7;
    const size_t base = (size_t)(bt * 32 + n) * 6144 + (size_t)h * 128;
    const u16* kp = kvb + base + sub * 16;
    u16x8 k0 = *(const u16x8*)kp;
    u16x8 k1 = *(const u16x8*)(kp + 8);
    float kv_[16]; float ss = 0.f;
    #pragma unroll
    for (int j = 0; j < 8; ++j) { kv_[j] = b2f(k0[j]); kv_[8 + j] = b2f(k1[j]); }
    #pragma unroll
    for (int j = 0; j < 16; ++j) ss += kv_[j] * kv_[j];
    ss += __shfl_xor(ss, 1); ss += __shfl_xor(ss, 2); ss += __shfl_xor(ss, 4);
    const float krs = rsqrtf(ss * (1.f / 128.f) + 1e-6f);
    u16x8 w0, w1;
    #pragma unroll
    for (int j = 0; j < 8; ++j) {
      const int d = sub * 16 + j;
      w0[j] = f2b(kv_[j] * krs * kw[d] * qw[d]);
      w1[j] = f2b(kv_[8 + j] * krs * kw[d + 8] * qw[d + 8]);
    }
    *(u16x8*)&Kn[n * 136 + sub * 16] = w0;
    *(u16x8*)&Kn[n * 136 + sub * 16 + 8] = w1;
  }
  {
    const int k = tid >> 3, dc = (tid & 7) * 16;
    const u16* vp = kvb + (size_t)(bt * 32 + k) * 6144 + (size_t)h * 128 + 3072 + dc;
    u16x8 v0 = *(const u16x8*)vp;
    u16x8 v1 = *(const u16x8*)(vp + 8);
    #pragma unroll
    for (int j = 0; j < 8; ++j) {
      Vt[(dc + j) * 40 + k] = v0[j];
      Vt[(dc + 8 + j) * 40 + k] = v1[j];
    }
  }
  __syncthreads();

  const int q0 = wave * 64;
  const int lr = lane & 15, lg = lane >> 4;

  for (int m = 0; m < 4; ++m) {
    const int qrow = q0 + m * 16 + lr;
    const u16* qp = qb + (size_t)(bt * 256 + qrow) * 3072 + (size_t)h * 128 + lg * 8;
    bf16x8 qf[4];
    #pragma unroll
    for (int k = 0; k < 4; ++k) qf[k] = *(const bf16x8*)(qp + k * 32);
    float ss = 0.f;
    #pragma unroll
    for (int k = 0; k < 4; ++k)
      #pragma unroll
      for (int j = 0; j < 8; ++j) { const float f = b2f((u16)qf[k][j]); ss += f * f; }
    ss += __shfl_xor(ss, 16); ss += __shfl_xor(ss, 32);
    const float qsc = rsqrtf(ss * (1.f / 128.f) + 1e-6f) * 0.08838834764831845f;
    #pragma unroll
    for (int k = 0; k < 4; ++k)
      #pragma unroll
      for (int j = 0; j < 8; ++j)
        qf[k][j] = (short)f2b(b2f((u16)qf[k][j]) * qsc);

    f32x4 s0 = {0.f, 0.f, 0.f, 0.f}, s1 = {0.f, 0.f, 0.f, 0.f};
    #pragma unroll
    for (int k = 0; k < 4; ++k) {
      bf16x8 kb0 = *(const bf16x8*)&Kn[(lr) * 136 + k * 32 + lg * 8];
      bf16x8 kb1 = *(const bf16x8*)&Kn[(16 + lr) * 136 + k * 32 + lg * 8];
      s0 = __builtin_amdgcn_mfma_f32_16x16x32_bf16(qf[k], kb0, s0, 0, 0, 0);
      s1 = __builtin_amdgcn_mfma_f32_16x16x32_bf16(qf[k], kb1, s1, 0, 0, 0);
    }

    float mx[4], sm[4], e0[4], e1[4];
    #pragma unroll
    for (int i = 0; i < 4; ++i) mx[i] = fmaxf(s0[i], s1[i]);
    #pragma unroll
    for (int o = 1; o <= 8; o <<= 1)
      #pragma unroll
      for (int i = 0; i < 4; ++i) mx[i] = fmaxf(mx[i], __shfl_xor(mx[i], o));
    #pragma unroll
    for (int i = 0; i < 4; ++i) {
      e0[i] = __expf(s0[i] - mx[i]);
      e1[i] = __expf(s1[i] - mx[i]);
      sm[i] = e0[i] + e1[i];
    }
    #pragma unroll
    for (int o = 1; o <= 8; o <<= 1)
      #pragma unroll
      for (int i = 0; i < 4; ++i) sm[i] += __shfl_xor(sm[i], o);
    #pragma unroll
    for (int i = 0; i < 4; ++i) {
      const float inv = 1.f / sm[i];
      const int pr = (q0 + m * 16 + lg * 4 + i) * 40;
      Pl[pr + lr] = f2b(e0[i] * inv);
      Pl[pr + 16 + lr] = f2b(e1[i] * inv);
    }
    asm volatile("s_waitcnt lgkmcnt(0)" ::: "memory");
    __builtin_amdgcn_sched_barrier(0);

    bf16x8 pf = *(const bf16x8*)&Pl[(q0 + m * 16 + lr) * 40 + lg * 8];
    f32x4 o_[8];
    #pragma unroll
    for (int n = 0; n < 8; ++n) {
      bf16x8 vb = *(const bf16x8*)&Vt[(n * 16 + lr) * 40 + lg * 8];
      o_[n] = __builtin_amdgcn_mfma_f32_16x16x32_bf16(
                pf, vb, (f32x4){0.f, 0.f, 0.f, 0.f}, 0, 0, 0);
    }

    u16* ow = &Ol[wave][0];
    #pragma unroll
    for (int n = 0; n < 8; ++n)
      #pragma unroll
      for (int i = 0; i < 4; ++i)
        ow[(lg * 4 + i) * 136 + n * 16 + lr] = f2b(o_[n][i]);
    asm volatile("s_waitcnt lgkmcnt(0)" ::: "memory");
    __builtin_amdgcn_sched_barrier(0);
    const int r = lane >> 2, cc = (lane & 3) * 32;
    u16* gout = attnb + (size_t)(bt * 256 + q0 + m * 16 + r) * 3072 + (size_t)h * 128 + cc;
    #pragma unroll
    for (int c = 0; c < 4; ++c)
      *(u16x8*)(gout + c * 8) = *(const u16x8*)&ow[r * 136 + cc + c * 8];
    asm volatile("s_waitcnt lgkmcnt(0)" ::: "memory");
    __builtin_amdgcn_sched_barrier(0);
  }
}

// =====================================================================
extern "C" void kernel_launch(void* const* d_in, const int* in_sizes, int n_in,
                              void* d_out, int out_size, void* d_ws, size_t ws_size,
                              hipStream_t stream) {
  const float* x    = (const float*)d_in[0];
  const float* mv   = (const float*)d_in[1];
  const float* mask = (const float*)d_in[2];
  const float* wkv  = (const float*)d_in[3];
  const float* bkv  = (const float*)d_in[4];
  const float* wq   = (const float*)d_in[5];
  const float* bq   = (const float*)d_in[6];
  const float* wo   = (const float*)d_in[7];
  const float* bo   = (const float*)d_in[8];
  const float* qnw  = (const float*)d_in[9];
  const float* knw  = (const float*)d_in[10];
  float* out = (float*)d_out;

  char* ws = (char*)d_ws;

  if (ws_size >= 176160768u) {
    // tier-1 layout
    u16* wqs  = (u16*)(ws);                  // 3072x3072 bf16
    u16* wkvs = (u16*)(ws + 18874368);       // 6144x3072 bf16
    u16* xf   = (u16*)(ws + 56623104);       // 8192x3072 bf16
    u16* xm   = (u16*)(ws + 106954752);      // 1024x3072 bf16
    u16* qbuf = (u16*)(ws + 113246208);      // 8192x3072 bf16
    u16* kvb  = (u16*)(ws + 163577856);      // 1024x6144 bf16 (end 176,160,768)
    u16* wos  = wqs;                         // reuse (dead after Q-GEMM)

    prep_kernel<<<11264, 256, 0, stream>>>(x, mv, xf, xm, wq, wqs, wkv, wkvs);
    gemm8p<0, u16><<<384, 512, 0, stream>>>(xf, wqs, bq, nullptr, qbuf, 8192, 3072, 3072);
    gemm256<0, u16><<<192, 256, 0, stream>>>(xm, wkvs, bkv, nullptr, kvb, 1024, 6144, 3072);
    attn_wcvt<<<1792, 256, 0, stream>>>(qbuf, kvb, qnw, knw, xf, wo, wos);
    gemm8p<1, float><<<384, 512, 0, stream>>>(xf, wos, bo, mask, out, 8192, 3072, 3072);
  } else if (ws_size >= 157286400u) {
    // tier-2
    u16* xf    = (u16*)(ws);
    u16* xm    = (u16*)(ws + 50331648);
    u16* qbuf  = (u16*)(ws + 56623104);
    u16* kvb   = (u16*)(ws + 106954752);
    u16* wslab = (u16*)(ws + 119537664);

    prep_kernel<<<9216, 256, 0, stream>>>(x, mv, xf, xm, wq, wslab, wkv, wslab);
    wcvt_kernel<<<2048, 256, 0, stream>>>(wq, wslab, 3072 * 3072 / 4);
    gemm8p<0, u16><<<384, 512, 0, stream>>>(xf, wslab, bq, nullptr, qbuf, 8192, 3072, 3072);
    wcvt_kernel<<<2048, 256, 0, stream>>>(wkv, wslab, 6144 * 3072 / 4);
    gemm256<0, u16><<<192, 256, 0, stream>>>(xm, wslab, bkv, nullptr, kvb, 1024, 6144, 3072);
    attn_wcvt<<<768, 256, 0, stream>>>(qbuf, kvb, qnw, knw, xf, wo, wslab);
    wcvt_kernel<<<2048, 256, 0, stream>>>(wo, wslab, 3072 * 3072 / 4);
    gemm8p<1, float><<<384, 512, 0, stream>>>(xf, wslab, bo, mask, out, 8192, 3072, 3072);
  } else {
    // tier-3: mixed fallback
    u16* xf   = (u16*)(ws);
    u16* xm   = (u16*)(ws + 50331648);
    u16* qbuf = (u16*)(ws + 56623104);
    u16* kvb  = (u16*)(ws + 106954752);

    prep_kernel<<<9216, 256, 0, stream>>>(x, mv, xf, xm, wq, xf, wkv, xf);
    gemm_mixed<0, u16><<<1536, 256, 0, stream>>>(xf, wq, bq, nullptr, qbuf, 8192, 3072, 3072);
    gemm_mixed<0, u16><<<384, 256, 0, stream>>>(xm, wkv, bkv, nullptr, kvb, 1024, 6144, 3072);
    attn_wcvt<<<768, 256, 0, stream>>>(qbuf, kvb, qnw, knw, xf, wo, xf);
    gemm_mixed<1, float><<<1536, 256, 0, stream>>>(xf, wo, bo, mask, out, 8192, 3072, 3072);
  }
}

// Round 12
// 494.140 us; speedup vs baseline: 1.0052x; 1.0052x over previous
//
#include <hip/hip_runtime.h>
#include <math.h>

typedef unsigned short u16;
typedef unsigned int u32;
typedef short bf16x8 __attribute__((ext_vector_type(8)));
typedef float f32x4 __attribute__((ext_vector_type(4)));
typedef u16 u16x4 __attribute__((ext_vector_type(4)));
typedef u16 u16x8 __attribute__((ext_vector_type(8)));
typedef u32 u32x4 __attribute__((ext_vector_type(4)));

// ---------- bf16 <-> f32 helpers ----------
static __device__ __forceinline__ float b2f(u16 u) {
  union { u32 i; float f; } v; v.i = ((u32)u) << 16; return v.f;
}
static __device__ __forceinline__ u16 f2b(float f) {
  union { float f; u32 i; } v; v.f = f;
  u32 r = v.i + 0x7fffu + ((v.i >> 16) & 1u);
  return (u16)(r >> 16);
}
static __device__ __forceinline__ void cvt16(const float* src, u16* dst, int i) {
  f32x4 v = *(const f32x4*)(src + (size_t)i * 4);
  u16x4 w; w.x = f2b(v.x); w.y = f2b(v.y); w.z = f2b(v.z); w.w = f2b(v.w);
  *(u16x4*)(dst + (size_t)i * 4) = w;
}

// ---------- async global -> LDS, 16B per lane ----------
static __device__ __forceinline__ void g2l16(const void* g, void* l) {
  typedef __attribute__((address_space(1))) const void gvoid;
  typedef __attribute__((address_space(3))) void lvoid;
  __builtin_amdgcn_global_load_lds((gvoid*)g, (lvoid*)l, 16, 0, 0);
}

// =====================================================================
// Standalone weight convert (tier-2/3).
// =====================================================================
__global__ __launch_bounds__(256)
void wcvt_kernel(const float* __restrict__ src, u16* __restrict__ dst, int n4)
{
  for (int i = blockIdx.x * 256 + threadIdx.x; i < n4; i += gridDim.x * 256)
    cvt16(src, dst, i);
}

// =====================================================================
// prep: blocks 0..9215 LayerNorm; 9216..10239 wq cvt; 10240..11263 wkv cvt.
// =====================================================================
__global__ __launch_bounds__(256)
void prep_kernel(const float* __restrict__ x, const float* __restrict__ mv,
                 u16* __restrict__ xf, u16* __restrict__ xm,
                 const float* __restrict__ wq, u16* __restrict__ wqs,
                 const float* __restrict__ wkv, u16* __restrict__ wkvs)
{
  const int b = blockIdx.x, tid = threadIdx.x;
  if (b >= 9216) {
    if (b < 10240) {
      const int n4 = 3072 * 3072 / 4;
      for (int i = (b - 9216) * 256 + tid; i < n4; i += 1024 * 256) cvt16(wq, wqs, i);
    } else {
      const int n4 = 6144 * 3072 / 4;
      for (int i = (b - 10240) * 256 + tid; i < n4; i += 1024 * 256) cvt16(wkv, wkvs, i);
    }
    return;
  }
  const float* src; u16* dst;
  if (b < 8192) { src = x + (size_t)b * 3072;          dst = xf + (size_t)b * 3072; }
  else          { src = mv + (size_t)(b - 8192) * 3072; dst = xm + (size_t)(b - 8192) * 3072; }

  f32x4 vals[3];
  #pragma unroll
  for (int i = 0; i < 3; ++i) vals[i] = *(const f32x4*)(src + tid * 4 + i * 1024);

  float s1 = 0.f, s2 = 0.f;
  #pragma unroll
  for (int i = 0; i < 3; ++i) {
    f32x4 v = vals[i];
    s1 += v.x + v.y + v.z + v.w;
    s2 += v.x * v.x + v.y * v.y + v.z * v.z + v.w * v.w;
  }
  #pragma unroll
  for (int o = 32; o > 0; o >>= 1) { s1 += __shfl_down(s1, o); s2 += __shfl_down(s2, o); }
  __shared__ float r1[4], r2[4];
  const int wv = tid >> 6, ln = tid & 63;
  if (ln == 0) { r1[wv] = s1; r2[wv] = s2; }
  __syncthreads();
  const float t1 = r1[0] + r1[1] + r1[2] + r1[3];
  const float t2 = r2[0] + r2[1] + r2[2] + r2[3];
  const float mu = t1 * (1.f / 3072.f);
  const float rs = rsqrtf(t2 * (1.f / 3072.f) - mu * mu + 1e-6f);
  #pragma unroll
  for (int i = 0; i < 3; ++i) {
    f32x4 v = vals[i]; u16x4 w;
    w.x = f2b((v.x - mu) * rs); w.y = f2b((v.y - mu) * rs);
    w.z = f2b((v.z - mu) * rs); w.w = f2b((v.w - mu) * rs);
    *(u16x4*)(dst + tid * 4 + i * 1024) = w;
  }
}

// =====================================================================
// gemm8p v2 (deep-pipeline): 256x256 tile, BK=64, 8 waves (2M x 4N).
// Read/MFMA side identical to refcheck'd R11. Staging re-timed for
// 3-phase issue->wait slack:
//   P1: (t+1)B h0+h1 -> d1   (d1.B dead since prev P8)
//   P4: (t+2)A h0+h1 -> d0   (d0.A last read P3)
//   P5: (t+2)B h0+h1 -> d0   (d0.B last read P4)
//   P8: (t+3)A h0+h1 -> d1   (d1.A last read P7)
// vmcnt(4) at P4 (retires t+1 = A@prevP8 + B@P1, keeps t+2.A) and at
// P8 (retires t+2, keeps t+3.A). Peak 12 loads in flight. Prologue:
// t0 x4 halves + t1.A, vmcnt(4). Final iter: P4 vmcnt(0), P8 skip.
// =====================================================================
template<int EPI, typename TOUT>
__global__ __launch_bounds__(512, 1)
void gemm8p(const u16* __restrict__ A, const u16* __restrict__ Wb,
            const float* __restrict__ bias, const float* __restrict__ mask,
            TOUT* __restrict__ C, int M, int N, int K)
{
  __shared__ __align__(16) u16 L[65536];   // 128 KB
  const int tid = threadIdx.x, wave = tid >> 6, lane = tid & 63;
  const int wr = wave >> 2, wc = wave & 3;       // 2 x 4 wave grid
  const int lr = lane & 15, lg = lane >> 4;

  const int nwg = gridDim.x;
  const int bid = (blockIdx.x & 7) * (nwg >> 3) + (blockIdx.x >> 3);
  const int nbx = N >> 8;
  const int brow = (bid / nbx) << 8;
  const int bcol = (bid % nbx) << 8;

  const u16* gA = A + (size_t)brow * K;
  const u16* gB = Wb + (size_t)bcol * K;

  // staging: round = 512 thr x 16B = 64 rows x 128B; 2 rounds/half-tile
  const int sr = tid >> 3;                        // 0..63 row in round
  const int sc = 8 * ((tid & 7) ^ (sr & 7));      // pre-swizzled src col
  // fragment read chunk offsets (phys = logical ^ (row&7))
  const int ch0 = 8 * (lg ^ (lr & 7));
  const int ch1 = 8 * ((4 + lg) ^ (lr & 7));

  f32x4 acc[8][4] = {};

  // stage one half-tile: sel 0=A,1=B; dbuf d, half h, K-tile T (2 gloads)
  auto SG = [&](int sel, int d, int h, int T) {
    const u16* g = (sel == 0 ? gA : gB) + (size_t)(h * 128 + sr) * K + T * 64 + sc;
    u16* l = &L[sel * 32768 + (d * 2 + h) * 8192 + tid * 8];
    g2l16(g, l);
    g2l16(g + (size_t)64 * K, l + 4096);
  };
  auto LDA = [&](int d, int mh, bf16x8 a[4][2]) {
    const u16* base = &L[(d * 2 + wr) * 8192 + mh * 4096 + lr * 64];
    #pragma unroll
    for (int mm = 0; mm < 4; ++mm) {
      a[mm][0] = *(const bf16x8*)&base[mm * 1024 + ch0];
      a[mm][1] = *(const bf16x8*)&base[mm * 1024 + ch1];
    }
  };
  auto LDB = [&](int d, int nh, bf16x8 b[2][2]) {
    const u16* base = &L[32768 + (d * 2 + (wc >> 1)) * 8192 + (wc & 1) * 4096 + nh * 2048 + lr * 64];
    #pragma unroll
    for (int nn = 0; nn < 2; ++nn) {
      b[nn][0] = *(const bf16x8*)&base[nn * 1024 + ch0];
      b[nn][1] = *(const bf16x8*)&base[nn * 1024 + ch1];
    }
  };

#define MM8P(mh, nh, a, b)                                                     \
  __builtin_amdgcn_s_setprio(1);                                               \
  _Pragma("unroll")                                                            \
  for (int mm = 0; mm < 4; ++mm)                                               \
    _Pragma("unroll")                                                          \
    for (int nn = 0; nn < 2; ++nn) {                                           \
      acc[(mh)*4+mm][(nh)*2+nn] = __builtin_amdgcn_mfma_f32_16x16x32_bf16(     \
          a[mm][0], b[nn][0], acc[(mh)*4+mm][(nh)*2+nn], 0, 0, 0);             \
      acc[(mh)*4+mm][(nh)*2+nn] = __builtin_amdgcn_mfma_f32_16x16x32_bf16(     \
          a[mm][1], b[nn][1], acc[(mh)*4+mm][(nh)*2+nn], 0, 0, 0);             \
    }                                                                          \
  __builtin_amdgcn_s_setprio(0);

#define BAR_PRE()                                                              \
  asm volatile("" ::: "memory");                                               \
  __builtin_amdgcn_s_barrier();                                                \
  asm volatile("s_waitcnt lgkmcnt(0)" ::: "memory");                           \
  __builtin_amdgcn_sched_barrier(0);

#define BAR_POST()                                                             \
  asm volatile("" ::: "memory");                                               \
  __builtin_amdgcn_s_barrier();                                                \
  __builtin_amdgcn_sched_barrier(0);

  // prologue: t0 all 4 halves -> d0; t1 A h0+h1 -> d1; retire t0 (keep 4)
  SG(0, 0, 0, 0); SG(0, 0, 1, 0); SG(1, 0, 0, 0); SG(1, 0, 1, 0);
  SG(0, 1, 0, 1); SG(0, 1, 1, 1);
  asm volatile("s_waitcnt vmcnt(4)" ::: "memory");
  __builtin_amdgcn_s_barrier();
  __builtin_amdgcn_sched_barrier(0);

  const int NI = K >> 7;     // iterations over K-tile pairs (BK=64)
  for (int i = 0; i < NI; ++i) {
    const int t = 2 * i;
    const bool pf = (i + 1) < NI;
    bf16x8 a[4][2], b[2][2];

    // P1: read A(d0,mh0)+B(d0,nh0); stage (t+1)B h0+h1 -> d1
    LDA(0, 0, a); LDB(0, 0, b);
    SG(1, 1, 0, t + 1); SG(1, 1, 1, t + 1);
    BAR_PRE(); MM8P(0, 0, a, b); BAR_POST();

    // P2: read B(d0,nh1)
    LDB(0, 1, b);
    BAR_PRE(); MM8P(0, 1, a, b); BAR_POST();

    // P3: read A(d0,mh1)
    LDA(0, 1, a);
    BAR_PRE(); MM8P(1, 1, a, b); BAR_POST();

    // P4: read B(d0,nh0); stage (t+2)A h0+h1 -> d0; retire tile t+1
    LDB(0, 0, b);
    if (pf) { SG(0, 0, 0, t + 2); SG(0, 0, 1, t + 2); }
    BAR_PRE(); MM8P(1, 0, a, b);
    if (pf) { asm volatile("s_waitcnt vmcnt(4)" ::: "memory"); }
    else    { asm volatile("s_waitcnt vmcnt(0)" ::: "memory"); }
    BAR_POST();

    // P5: read A(d1,mh0)+B(d1,nh0); stage (t+2)B h0+h1 -> d0
    LDA(1, 0, a); LDB(1, 0, b);
    if (pf) { SG(1, 0, 0, t + 2); SG(1, 0, 1, t + 2); }
    BAR_PRE(); MM8P(0, 0, a, b); BAR_POST();

    // P6: read B(d1,nh1)
    LDB(1, 1, b);
    BAR_PRE(); MM8P(0, 1, a, b); BAR_POST();

    // P7: read A(d1,mh1)
    LDA(1, 1, a);
    BAR_PRE(); MM8P(1, 1, a, b); BAR_POST();

    // P8: read B(d1,nh0); stage (t+3)A h0+h1 -> d1; retire tile t+2
    LDB(1, 0, b);
    if (pf) { SG(0, 1, 0, t + 3); SG(0, 1, 1, t + 3); }
    BAR_PRE(); MM8P(1, 0, a, b);
    if (pf) { asm volatile("s_waitcnt vmcnt(4)" ::: "memory"); }
    BAR_POST();
  }

#undef MM8P
#undef BAR_PRE
#undef BAR_POST

  // epilogue: D row = 4*(lane>>4)+i, col = lane&15 (m89-verified)
  #pragma unroll
  for (int m = 0; m < 8; ++m) {
    const int row = brow + wr * 128 + m * 16 + (lg << 2);
    #pragma unroll
    for (int n = 0; n < 4; ++n) {
      const int col = bcol + wc * 64 + n * 16 + lr;
      const float bv = bias[col];
      #pragma unroll
      for (int i = 0; i < 4; ++i) {
        float v = acc[m][n][i] + bv;
        if (EPI == 1) v *= mask[row + i];
        if constexpr (__is_same(TOUT, u16))
          C[(size_t)(row + i) * N + col] = f2b(v);
        else
          C[(size_t)(row + i) * N + col] = v;
      }
    }
  }
}

// =====================================================================
// gemm256 (R5-verified): 256x128 tile, BK=32, 4 waves, 3-buf rotation,
// counted vmcnt(6). Used for the KV GEMM (small M).
// =====================================================================
template<int EPI, typename TOUT>
__global__ __launch_bounds__(256, 2)
void gemm256(const u16* __restrict__ A, const u16* __restrict__ Wb,
             const float* __restrict__ bias, const float* __restrict__ mask,
             TOUT* __restrict__ C, int M, int N, int K)
{
  __shared__ __align__(16) u16 L[36864];
  const int tid = threadIdx.x, wave = tid >> 6, lane = tid & 63;

  const int nwg = gridDim.x;
  const int bid = (blockIdx.x & 7) * (nwg >> 3) + (blockIdx.x >> 3);
  const int nbx = N >> 7;
  const int brow = (bid / nbx) << 8;
  const int bcol = (bid % nbx) << 7;
  const int wr = wave >> 1, wc = wave & 1;

  const u16* gA = A + (size_t)brow * K;
  const u16* gB = Wb + (size_t)bcol * K;

  const int srow = tid >> 2;
  const int scol = 8 * ((lane & 3) ^ ((lane >> 3) & 3));
  const int rcoff = 8 * ((lane >> 4) ^ ((lane >> 1) & 3));

  f32x4 acc[8][4] = {};

  auto STAGE = [&](int b, int tk) {
    u16* bufA = &L[b * 12288];
    u16* bufB = bufA + 8192;
    const u16* srcA = gA + tk + scol;
    const u16* srcB = gB + tk + scol;
    #pragma unroll
    for (int j = 0; j < 4; ++j)
      g2l16(srcA + (size_t)(j * 64 + srow) * K, bufA + (j * 64 + wave * 16) * 32);
    #pragma unroll
    for (int j = 0; j < 2; ++j)
      g2l16(srcB + (size_t)(j * 64 + srow) * K, bufB + (j * 64 + wave * 16) * 32);
  };

  auto COMPUTE = [&](int b) {
    const u16* bufA = &L[b * 12288];
    const u16* bufB = bufA + 8192;
    bf16x8 af[8], bfv[4];
    #pragma unroll
    for (int m = 0; m < 8; ++m)
      af[m] = *(const bf16x8*)&bufA[(wr * 128 + m * 16 + (lane & 15)) * 32 + rcoff];
    #pragma unroll
    for (int n = 0; n < 4; ++n)
      bfv[n] = *(const bf16x8*)&bufB[(wc * 64 + n * 16 + (lane & 15)) * 32 + rcoff];
    __builtin_amdgcn_s_setprio(1);
    #pragma unroll
    for (int m = 0; m < 8; ++m)
      #pragma unroll
      for (int n = 0; n < 4; ++n)
        acc[m][n] = __builtin_amdgcn_mfma_f32_16x16x32_bf16(af[m], bfv[n], acc[m][n], 0, 0, 0);
    __builtin_amdgcn_s_setprio(0);
  };

  STAGE(0, 0);
  STAGE(1, 32);
  asm volatile("s_waitcnt vmcnt(6)" ::: "memory");
  __builtin_amdgcn_s_barrier();
  __builtin_amdgcn_sched_barrier(0);

  const int NT = K >> 5;
  int cur = 0;
  for (int t = 0; t < NT; ++t) {
    const bool pf = (t + 2) < NT;
    if (pf) {
      int nb = cur + 2; if (nb >= 3) nb -= 3;
      STAGE(nb, (t + 2) << 5);
    }
    COMPUTE(cur);
    if (pf) asm volatile("s_waitcnt vmcnt(6)" ::: "memory");
    else    asm volatile("s_waitcnt vmcnt(0)" ::: "memory");
    __builtin_amdgcn_s_barrier();
    __builtin_amdgcn_sched_barrier(0);
    if (++cur == 3) cur = 0;
  }

  #pragma unroll
  for (int m = 0; m < 8; ++m) {
    const int row = brow + wr * 128 + m * 16 + ((lane >> 4) << 2);
    #pragma unroll
    for (int n = 0; n < 4; ++n) {
      const int col = bcol + wc * 64 + n * 16 + (lane & 15);
      const float bv = bias[col];
      #pragma unroll
      for (int i = 0; i < 4; ++i) {
        float v = acc[m][n][i] + bv;
        if (EPI == 1) v *= mask[row + i];
        if constexpr (__is_same(TOUT, u16))
          C[(size_t)(row + i) * N + col] = f2b(v);
        else
          C[(size_t)(row + i) * N + col] = v;
      }
    }
  }
}

// =====================================================================
// gemm192 (R9-verified, ~160us on O-GEMM): 128x192 tile, BK=32, 4 waves,
// per-wave 64x96, 3-buf, counted vmcnt(5). Grid 1024 = 2.0 generations.
// =====================================================================
template<int EPI, typename TOUT>
__global__ __launch_bounds__(256, 2)
void gemm192(const u16* __restrict__ A, const u16* __restrict__ Wb,
             const float* __restrict__ bias, const float* __restrict__ mask,
             TOUT* __restrict__ C, int M, int N, int K)
{
  __shared__ __align__(16) u16 L[30720];
  const int tid = threadIdx.x, wave = tid >> 6, lane = tid & 63;
  const int nwg = gridDim.x;
  const int tb = (blockIdx.x & 7) * (nwg >> 3) + (blockIdx.x >> 3);
  const int nbx = N / 192;
  const int brow = (tb / nbx) << 7;
  const int bcol = (tb % nbx) * 192;
  const int wr = wave >> 1, wc = wave & 1;

  const u16* gA = A + (size_t)brow * K;
  const u16* gB = Wb + (size_t)bcol * K;

  const int srow = tid >> 2;
  const int scol = 8 * ((lane & 3) ^ ((lane >> 3) & 3));
  const int rcoff = 8 * ((lane >> 4) ^ ((lane >> 1) & 3));
  const int lr = lane & 15;

  f32x4 acc[4][6] = {};

  auto STAGE = [&](int b, int tk) {
    u16* bufA = &L[b * 10240];
    u16* bufB = bufA + 4096;
    const u16* srcA = gA + tk + scol;
    const u16* srcB = gB + tk + scol;
    #pragma unroll
    for (int j = 0; j < 2; ++j)
      g2l16(srcA + (size_t)(j * 64 + srow) * K, bufA + (j * 64 + wave * 16) * 32);
    #pragma unroll
    for (int j = 0; j < 3; ++j)
      g2l16(srcB + (size_t)(j * 64 + srow) * K, bufB + (j * 64 + wave * 16) * 32);
  };

  auto COMPUTE = [&](int b) {
    const u16* bufA = &L[b * 10240];
    const u16* bufB = bufA + 4096;
    bf16x8 af[4], bfv[6];
    #pragma unroll
    for (int m = 0; m < 4; ++m)
      af[m] = *(const bf16x8*)&bufA[(wr * 64 + m * 16 + lr) * 32 + rcoff];
    #pragma unroll
    for (int n = 0; n < 6; ++n)
      bfv[n] = *(const bf16x8*)&bufB[(wc * 96 + n * 16 + lr) * 32 + rcoff];
    __builtin_amdgcn_s_setprio(1);
    #pragma unroll
    for (int m = 0; m < 4; ++m)
      #pragma unroll
      for (int n = 0; n < 6; ++n)
        acc[m][n] = __builtin_amdgcn_mfma_f32_16x16x32_bf16(af[m], bfv[n], acc[m][n], 0, 0, 0);
    __builtin_amdgcn_s_setprio(0);
  };

  STAGE(0, 0);
  STAGE(1, 32);
  asm volatile("s_waitcnt vmcnt(5)" ::: "memory");
  __builtin_amdgcn_s_barrier();
  __builtin_amdgcn_sched_barrier(0);

  const int NT = K >> 5;
  int cur = 0;
  for (int t = 0; t < NT; ++t) {
    const bool pf = (t + 2) < NT;
    if (pf) {
      int nb = cur + 2; if (nb >= 3) nb -= 3;
      STAGE(nb, (t + 2) << 5);
    }
    COMPUTE(cur);
    if (pf) asm volatile("s_waitcnt vmcnt(5)" ::: "memory");
    else    asm volatile("s_waitcnt vmcnt(0)" ::: "memory");
    __builtin_amdgcn_s_barrier();
    __builtin_amdgcn_sched_barrier(0);
    if (++cur == 3) cur = 0;
  }

  #pragma unroll
  for (int m = 0; m < 4; ++m) {
    const int row = brow + wr * 64 + m * 16 + ((lane >> 4) << 2);
    #pragma unroll
    for (int n = 0; n < 6; ++n) {
      const int col = bcol + wc * 96 + n * 16 + lr;
      const float bv = bias[col];
      #pragma unroll
      for (int i = 0; i < 4; ++i) {
        float v = acc[m][n][i] + bv;
        if (EPI == 1) v *= mask[row + i];
        if constexpr (__is_same(TOUT, u16))
          C[(size_t)(row + i) * N + col] = f2b(v);
        else
          C[(size_t)(row + i) * N + col] = v;
      }
    }
  }
}

// =====================================================================
// Fallback mixed GEMM (W fp32 reg-staged cvt) — tier-3 only.
// =====================================================================
template<int EPI, typename TOUT>
__global__ __launch_bounds__(256)
void gemm_mixed(const u16* __restrict__ A, const float* __restrict__ W,
                const float* __restrict__ bias, const float* __restrict__ mask,
                TOUT* __restrict__ C, int M, int N, int K)
{
  __shared__ __align__(16) u16 lA[4096];
  __shared__ __align__(16) u16 lB[4096];
  const int tid = threadIdx.x, wave = tid >> 6, lane = tid & 63;
  const int nbx = N >> 7;
  const int brow = (blockIdx.x / nbx) << 7;
  const int bcol = (blockIdx.x % nbx) << 7;
  const int wr = wave >> 1, wc = wave & 1;

  f32x4 acc[4][4] = {};
  const u16* gA = A + (size_t)brow * K;
  const float* gB = W + (size_t)bcol * K;
  const int br = tid >> 1, bk0 = (tid & 1) << 4;
  const float* bsrc0 = gB + (size_t)br * K + bk0;
  u16* bdst = &lB[br * 32 + bk0];

  for (int tk = 0; tk < K; tk += 32) {
    #pragma unroll
    for (int j = 0; j < 2; ++j) {
      const int c = j * 256 + wave * 64 + lane;
      const int r = c >> 2, k8 = (c & 3) << 3;
      g2l16(gA + (size_t)r * K + tk + k8, (char*)lA + (size_t)(j * 256 + wave * 64) * 16);
    }
    {
      const float* src = bsrc0 + tk;
      #pragma unroll
      for (int j = 0; j < 4; ++j) {
        f32x4 v = *(const f32x4*)(src + 4 * j);
        u16x4 w; w.x = f2b(v.x); w.y = f2b(v.y); w.z = f2b(v.z); w.w = f2b(v.w);
        *(u16x4*)(bdst + 4 * j) = w;
      }
    }
    __syncthreads();

    bf16x8 af[4], bfr[4];
    #pragma unroll
    for (int m = 0; m < 4; ++m)
      af[m] = *(const bf16x8*)&lA[(wr * 64 + m * 16 + (lane & 15)) * 32 + ((lane >> 4) << 3)];
    #pragma unroll
    for (int n = 0; n < 4; ++n)
      bfr[n] = *(const bf16x8*)&lB[(wc * 64 + n * 16 + (lane & 15)) * 32 + ((lane >> 4) << 3)];
    #pragma unroll
    for (int m = 0; m < 4; ++m)
      #pragma unroll
      for (int n = 0; n < 4; ++n)
        acc[m][n] = __builtin_amdgcn_mfma_f32_16x16x32_bf16(af[m], bfr[n], acc[m][n], 0, 0, 0);
    __syncthreads();
  }

  #pragma unroll
  for (int m = 0; m < 4; ++m) {
    const int row = brow + wr * 64 + m * 16 + ((lane >> 4) << 2);
    #pragma unroll
    for (int n = 0; n < 4; ++n) {
      const int col = bcol + wc * 64 + n * 16 + (lane & 15);
      const float bv = bias[col];
      #pragma unroll
      for (int i = 0; i < 4; ++i) {
        float v = acc[m][n][i] + bv;
        if (EPI == 1) v *= mask[row + i];
        if constexpr (__is_same(TOUT, u16))
          C[(size_t)(row + i) * N + col] = f2b(v);
        else
          C[(size_t)(row + i) * N + col] = v;
      }
    }
  }
}

// =====================================================================
// attn_wcvt: blocks 0..767 MFMA attention (verified R7 body);
// blocks 768..1791 wo fp32->bf16.
// =====================================================================
__global__ __launch_bounds__(256)
void attn_wcvt(const u16* __restrict__ qb, const u16* __restrict__ kvb,
               const float* __restrict__ qw, const float* __restrict__ kw,
               u16* __restrict__ attnb,
               const float* __restrict__ wo, u16* __restrict__ wos)
{
  __shared__ __align__(16) u16 Kn[32 * 136];
  __shared__ __align__(16) u16 Vt[128 * 40];
  __shared__ __align__(16) u16 Pl[256 * 40];
  __shared__ __align__(16) u16 Ol[4][16 * 136];
  const int tid = threadIdx.x;
  if (blockIdx.x >= 768) {
    const int n4 = 3072 * 3072 / 4;
    for (int i = (blockIdx.x - 768) * 256 + tid; i < n4; i += 1024 * 256)
      cvt16(wo, wos, i);
    return;
  }
  const int wave = tid >> 6, lane = tid & 63;
  const int h = blockIdx.x % 24;
  const int bt = blockIdx.x / 24;

  {
    const int n = tid >> 3, sub = tid & 7;
    const size_t base = (size_t)(bt * 32 + n) * 6144 + (size_t)h * 128;
    const u16* kp = kvb + base + sub * 16;
    u16x8 k0 = *(const u16x8*)kp;
    u16x8 k1 = *(const u16x8*)(kp + 8);
    float kv_[16]; float ss = 0.f;
    #pragma unroll
    for (int j = 0; j < 8; ++j) { kv_[j] = b2f(k0[j]); kv_[8 + j] = b2f(k1[j]); }
    #pragma unroll
    for (int j = 0; j < 16; ++j) ss += kv_[j] * kv_[j];
    ss += __shfl_xor(ss, 1); ss += __shfl_xor(ss, 2); ss += __shfl_xor(ss, 4);
    const float krs = rsqrtf(ss * (1.f / 128.f) + 1e-6f);
    u16x8 w0, w1;
    #pragma unroll
    for (int j = 0; j < 8; ++j) {
      const int d = sub * 16 + j;
      w0[j] = f2b(kv_[j] * krs * kw[d] * qw[d]);
      w1[j] = f2b(kv_[8 + j] * krs * kw[d + 8] * qw[d + 8]);
    }
    *(u16x8*)&Kn[n * 136 + sub * 16] = w0;
    *(u16x8*)&Kn[n * 136 + sub * 16 + 8] = w1;
  }
  {
    const int k = tid >> 3, dc = (tid & 7) * 16;
    const u16* vp = kvb + (size_t)(bt * 32 + k) * 6144 + (size_t)h * 128 + 3072 + dc;
    u16x8 v0 = *(const u16x8*)vp;
    u16x8 v1 = *(const u16x8*)(vp + 8);
    #pragma unroll
    for (int j = 0; j < 8; ++j) {
      Vt[(dc + j) * 40 + k] = v0[j];
      Vt[(dc + 8 + j) * 40 + k] = v1[j];
    }
  }
  __syncthreads();

  const int q0 = wave * 64;
  const int lr = lane & 15, lg = lane >> 4;

  for (int m = 0; m < 4; ++m) {
    const int qrow = q0 + m * 16 + lr;
    const u16* qp = qb + (size_t)(bt * 256 + qrow) * 3072 + (size_t)h * 128 + lg * 8;
    bf16x8 qf[4];
    #pragma unroll
    for (int k = 0; k < 4; ++k) qf[k] = *(const bf16x8*)(qp + k * 32);
    float ss = 0.f;
    #pragma unroll
    for (int k = 0; k < 4; ++k)
      #pragma unroll
      for (int j = 0; j < 8; ++j) { const float f = b2f((u16)qf[k][j]); ss += f * f; }
    ss += __shfl_xor(ss, 16); ss += __shfl_xor(ss, 32);
    const float qsc = rsqrtf(ss * (1.f / 128.f) + 1e-6f) * 0.08838834764831845f;
    #pragma unroll
    for (int k = 0; k < 4; ++k)
      #pragma unroll
      for (int j = 0; j < 8; ++j)
        qf[k][j] = (short)f2b(b2f((u16)qf[k][j]) * qsc);

    f32x4 s0 = {0.f, 0.f, 0.f, 0.f}, s1 = {0.f, 0.f, 0.f, 0.f};
    #pragma unroll
    for (int k = 0; k < 4; ++k) {
      bf16x8 kb0 = *(const bf16x8*)&Kn[(lr) * 136 + k * 32 + lg * 8];
      bf16x8 kb1 = *(const bf16x8*)&Kn[(16 + lr) * 136 + k * 32 + lg * 8];
      s0 = __builtin_amdgcn_mfma_f32_16x16x32_bf16(qf[k], kb0, s0, 0, 0, 0);
      s1 = __builtin_amdgcn_mfma_f32_16x16x32_bf16(qf[k], kb1, s1, 0, 0, 0);
    }

    float mx[4], sm[4], e0[4], e1[4];
    #pragma unroll
    for (int i = 0; i < 4; ++i) mx[i] = fmaxf(s0[i], s1[i]);
    #pragma unroll
    for (int o = 1; o <= 8; o <<= 1)
      #pragma unroll
      for (int i = 0; i < 4; ++i) mx[i] = fmaxf(mx[i], __shfl_xor(mx[i], o));
    #pragma unroll
    for (int i = 0; i < 4; ++i) {
      e0[i] = __expf(s0[i] - mx[i]);
      e1[i] = __expf(s1[i] - mx[i]);
      sm[i] = e0[i] + e1[i];
    }
    #pragma unroll
    for (int o = 1; o <= 8; o <<= 1)
      #pragma unroll
      for (int i = 0; i < 4; ++i) sm[i] += __shfl_xor(sm[i], o);
    #pragma unroll
    for (int i = 0; i < 4; ++i) {
      const float inv = 1.f / sm[i];
      const int pr = (q0 + m * 16 + lg * 4 + i) * 40;
      Pl[pr + lr] = f2b(e0[i] * inv);
      Pl[pr + 16 + lr] = f2b(e1[i] * inv);
    }
    asm volatile("s_waitcnt lgkmcnt(0)" ::: "memory");
    __builtin_amdgcn_sched_barrier(0);

    bf16x8 pf = *(const bf16x8*)&Pl[(q0 + m * 16 + lr) * 40 + lg * 8];
    f32x4 o_[8];
    #pragma unroll
    for (int n = 0; n < 8; ++n) {
      bf16x8 vb = *(const bf16x8*)&Vt[(n * 16 + lr) * 40 + lg * 8];
      o_[n] = __builtin_amdgcn_mfma_f32_16x16x32_bf16(
                pf, vb, (f32x4){0.f, 0.f, 0.f, 0.f}, 0, 0, 0);
    }

    u16* ow = &Ol[wave][0];
    #pragma unroll
    for (int n = 0; n < 8; ++n)
      #pragma unroll
      for (int i = 0; i < 4; ++i)
        ow[(lg * 4 + i) * 136 + n * 16 + lr] = f2b(o_[n][i]);
    asm volatile("s_waitcnt lgkmcnt(0)" ::: "memory");
    __builtin_amdgcn_sched_barrier(0);
    const int r = lane >> 2, cc = (lane & 3) * 32;
    u16* gout = attnb + (size_t)(bt * 256 + q0 + m * 16 + r) * 3072 + (size_t)h * 128 + cc;
    #pragma unroll
    for (int c = 0; c < 4; ++c)
      *(u16x8*)(gout + c * 8) = *(const u16x8*)&ow[r * 136 + cc + c * 8];
    asm volatile("s_waitcnt lgkmcnt(0)" ::: "memory");
    __builtin_amdgcn_sched_barrier(0);
  }
}

// =====================================================================
extern "C" void kernel_launch(void* const* d_in, const int* in_sizes, int n_in,
                              void* d_out, int out_size, void* d_ws, size_t ws_size,
                              hipStream_t stream) {
  const float* x    = (const float*)d_in[0];
  const float* mv   = (const float*)d_in[1];
  const float* mask = (const float*)d_in[2];
  const float* wkv  = (const float*)d_in[3];
  const float* bkv  = (const float*)d_in[4];
  const float* wq   = (const float*)d_in[5];
  const float* bq   = (const float*)d_in[6];
  const float* wo   = (const float*)d_in[7];
  const float* bo   = (const float*)d_in[8];
  const float* qnw  = (const float*)d_in[9];
  const float* knw  = (const float*)d_in[10];
  float* out = (float*)d_out;

  char* ws = (char*)d_ws;

  if (ws_size >= 176160768u) {
    // tier-1 layout
    u16* wqs  = (u16*)(ws);                  // 3072x3072 bf16
    u16* wkvs = (u16*)(ws + 18874368);       // 6144x3072 bf16
    u16* xf   = (u16*)(ws + 56623104);       // 8192x3072 bf16
    u16* xm   = (u16*)(ws + 106954752);      // 1024x3072 bf16
    u16* qbuf = (u16*)(ws + 113246208);      // 8192x3072 bf16
    u16* kvb  = (u16*)(ws + 163577856);      // 1024x6144 bf16 (end 176,160,768)
    u16* wos  = wqs;                         // reuse (dead after Q-GEMM)

    prep_kernel<<<11264, 256, 0, stream>>>(x, mv, xf, xm, wq, wqs, wkv, wkvs);
    gemm8p<0, u16><<<384, 512, 0, stream>>>(xf, wqs, bq, nullptr, qbuf, 8192, 3072, 3072);
    gemm256<0, u16><<<192, 256, 0, stream>>>(xm, wkvs, bkv, nullptr, kvb, 1024, 6144, 3072);
    attn_wcvt<<<1792, 256, 0, stream>>>(qbuf, kvb, qnw, knw, xf, wo, wos);
    gemm192<1, float><<<1024, 256, 0, stream>>>(xf, wos, bo, mask, out, 8192, 3072, 3072);
  } else if (ws_size >= 157286400u) {
    // tier-2
    u16* xf    = (u16*)(ws);
    u16* xm    = (u16*)(ws + 50331648);
    u16* qbuf  = (u16*)(ws + 56623104);
    u16* kvb   = (u16*)(ws + 106954752);
    u16* wslab = (u16*)(ws + 119537664);

    prep_kernel<<<9216, 256, 0, stream>>>(x, mv, xf, xm, wq, wslab, wkv, wslab);
    wcvt_kernel<<<2048, 256, 0, stream>>>(wq, wslab, 3072 * 3072 / 4);
    gemm8p<0, u16><<<384, 512, 0, stream>>>(xf, wslab, bq, nullptr, qbuf, 8192, 3072, 3072);
    wcvt_kernel<<<2048, 256, 0, stream>>>(wkv, wslab, 6144 * 3072 / 4);
    gemm256<0, u16><<<192, 256, 0, stream>>>(xm, wslab, bkv, nullptr, kvb, 1024, 6144, 3072);
    attn_wcvt<<<768, 256, 0, stream>>>(qbuf, kvb, qnw, knw, xf, wo, wslab);
    wcvt_kernel<<<2048, 256, 0, stream>>>(wo, wslab, 3072 * 3072 / 4);
    gemm192<1, float><<<1024, 256, 0, stream>>>(xf, wslab, bo, mask, out, 8192, 3072, 3072);
  } else {
    // tier-3: mixed fallback
    u16* xf   = (u16*)(ws);
    u16* xm   = (u16*)(ws + 50331648);
    u16* qbuf = (u16*)(ws + 56623104);
    u16* kvb  = (u16*)(ws + 106954752);

    prep_kernel<<<9216, 256, 0, stream>>>(x, mv, xf, xm, wq, xf, wkv, xf);
    gemm_mixed<0, u16><<<1536, 256, 0, stream>>>(xf, wq, bq, nullptr, qbuf, 8192, 3072, 3072);
    gemm_mixed<0, u16><<<384, 256, 0, stream>>>(xm, wkv, bkv, nullptr, kvb, 1024, 6144, 3072);
    attn_wcvt<<<768, 256, 0, stream>>>(qbuf, kvb, qnw, knw, xf, wo, xf);
    gemm_mixed<1, float><<<1536, 256, 0, stream>>>(xf, wo, bo, mask, out, 8192, 3072, 3072);
  }
}